// Round 3
// baseline (4392.183 us; speedup 1.0000x reference)
//
#include <hip/hip_runtime.h>

#define NN 20000
#define EE 120000
#define BB 4
#define CH 256

typedef unsigned int uint;
typedef unsigned short ushort;

typedef __attribute__((ext_vector_type(8))) short bf16x8_t;
typedef __attribute__((ext_vector_type(4))) float f32x4;

__device__ __forceinline__ float bf2f(ushort h) {
    union { uint u; float f; } v; v.u = ((uint)h) << 16; return v.f;
}
__device__ __forceinline__ ushort f2bf(float f) {
    union { float f; uint u; } v; v.f = f;
    uint u = v.u;
    uint r = (u + 0x7fffu + ((u >> 16) & 1u)) >> 16;
    return (ushort)r;
}

// ---------------- CSR build ----------------

__global__ __launch_bounds__(256) void init_zero_kernel(int* cnt, int* fill) {
    int i = blockIdx.x * 256 + threadIdx.x;
    if (i < BB * NN) { cnt[i] = 0; fill[i] = 0; }
}

__global__ __launch_bounds__(256) void count_kernel(const int* __restrict__ edge, int* cnt) {
    int i = blockIdx.x * 256 + threadIdx.x;
    if (i >= BB * EE) return;
    int b = i / EE, e = i - b * EE;
    int dst = edge[(size_t)b * 2 * EE + EE + e];
    atomicAdd(&cnt[b * NN + dst], 1);
}

__global__ __launch_bounds__(256) void dinv_kernel(const int* __restrict__ cnt, float* dinv) {
    int i = blockIdx.x * 256 + threadIdx.x;
    if (i < BB * NN) dinv[i] = rsqrtf((float)(cnt[i] + 1));
}

__global__ __launch_bounds__(256) void scan_kernel(const int* __restrict__ cnt, int* rowptr) {
    int b = blockIdx.x;
    int t = threadIdx.x;
    int lane = t & 63, wv = t >> 6;
    __shared__ int wsum[4];
    int carry = 0;
    for (int base = 0; base < NN; base += 256) {
        int v = (base + t < NN) ? cnt[b * NN + base + t] : 0;
        int incl = v;
        #pragma unroll
        for (int off = 1; off < 64; off <<= 1) {
            int u = __shfl_up(incl, off, 64);
            if (lane >= off) incl += u;
        }
        if (lane == 63) wsum[wv] = incl;
        __syncthreads();
        int wadd = 0;
        for (int w2 = 0; w2 < wv; w2++) wadd += wsum[w2];
        int tot = wsum[0] + wsum[1] + wsum[2] + wsum[3];
        if (base + t < NN) rowptr[(size_t)b * (NN + 1) + base + t] = carry + wadd + incl - v;
        carry += tot;
        __syncthreads();
    }
    if (t == 0) rowptr[(size_t)b * (NN + 1) + NN] = carry;
}

__global__ __launch_bounds__(256) void fill_kernel(const int* __restrict__ edge,
                                                   const int* __restrict__ rowptr,
                                                   int* fill, int* colidx) {
    int i = blockIdx.x * 256 + threadIdx.x;
    if (i >= BB * EE) return;
    int b = i / EE, e = i - b * EE;
    int src = edge[(size_t)b * 2 * EE + e];
    int dst = edge[(size_t)b * 2 * EE + EE + e];
    int pos = rowptr[(size_t)b * (NN + 1) + dst] + atomicAdd(&fill[b * NN + dst], 1);
    colidx[(size_t)b * EE + pos] = src;
}

// ---------------- weight prep (float32 -> bf16) ----------------

// plain square transpose: src float [256][256] k-major -> dst bf16 [n][k]
__global__ __launch_bounds__(256) void wt_sq_kernel(const float* __restrict__ src,
                                                    ushort* __restrict__ dst) {
    int i = blockIdx.x * 256 + threadIdx.x;
    if (i >= 65536) return;
    int n = i >> 8, k = i & 255;
    dst[i] = f2bf(src[(k << 8) + n]);
}

// concat [W;Ws] per layer: dst bf16 [12][256 n][512 k]
__global__ __launch_bounds__(256) void wt_cat_kernel(const float* __restrict__ W,
                                                     const float* __restrict__ Ws,
                                                     ushort* __restrict__ dst) {
    int i = blockIdx.x * 256 + threadIdx.x;
    if (i >= 12 * 256 * 512) return;
    int mat = i >> 17;
    int rem = i & 131071;
    int n = rem >> 9, k = rem & 511;
    float v = (k < 256) ? W[(mat << 16) + (k << 8) + n]
                        : Ws[(mat << 16) + ((k - 256) << 8) + n];
    dst[i] = f2bf(v);
}

// src float [963][256] -> dst bf16 [256][1024] (zero-padded K)
__global__ __launch_bounds__(256) void wt_lin_kernel(const float* __restrict__ src,
                                                     ushort* __restrict__ dst) {
    int i = blockIdx.x * 256 + threadIdx.x;
    if (i >= 256 * 1024) return;
    int n = i >> 10, k = i & 1023;
    dst[i] = (k < 963) ? f2bf(src[k * 256 + n]) : (ushort)0;
}

// x float [80000][963] -> xp bf16 [80000][1024] zero-padded
__global__ __launch_bounds__(256) void pad_x_kernel(const float* __restrict__ x,
                                                    ushort* __restrict__ xp) {
    size_t i = (size_t)blockIdx.x * 256 + threadIdx.x;
    if (i >= (size_t)BB * NN * 1024) return;
    size_t row = i >> 10;
    int k = (int)(i & 1023);
    xp[i] = (k < 963) ? f2bf(x[row * 963 + k]) : (ushort)0;
}

// ---------------- gather: us[d] = [ P@h (256ch) | h[symm] (256ch, optional) ] ----------------
// one wave per node; lane handles 4 channels

__global__ __launch_bounds__(256) void gather_kernel(const ushort* __restrict__ h,
                                                     const int* __restrict__ symm,
                                                     const float* __restrict__ dinv,
                                                     const int* __restrict__ rowptr,
                                                     const int* __restrict__ colidx,
                                                     ushort* __restrict__ us,
                                                     int stride) {  // 256 (u only) or 512 (u|s)
    int wv = threadIdx.x >> 6, lane = threadIdx.x & 63;
    int d = blockIdx.x * 4 + wv;
    int b = blockIdx.y;
    const ushort* hb = h + (size_t)b * NN * CH;
    const float* dv = dinv + b * NN;
    int co = lane * 4;
    int r0 = rowptr[(size_t)b * (NN + 1) + d];
    int r1 = rowptr[(size_t)b * (NN + 1) + d + 1];
    float dd = dv[d];
    const int* cb = colidx + (size_t)b * EE;
    float a0, a1, a2, a3;
    {   // self loop
        float w = dd * dd;
        uint2 v = *(const uint2*)(hb + (size_t)d * CH + co);
        a0 = w * bf2f((ushort)(v.x & 0xffff));
        a1 = w * bf2f((ushort)(v.x >> 16));
        a2 = w * bf2f((ushort)(v.y & 0xffff));
        a3 = w * bf2f((ushort)(v.y >> 16));
    }
    for (int j = r0; j < r1; j++) {
        int s = cb[j];
        float w = dv[s] * dd;
        uint2 v = *(const uint2*)(hb + (size_t)s * CH + co);
        a0 += w * bf2f((ushort)(v.x & 0xffff));
        a1 += w * bf2f((ushort)(v.x >> 16));
        a2 += w * bf2f((ushort)(v.y & 0xffff));
        a3 += w * bf2f((ushort)(v.y >> 16));
    }
    size_t orow = ((size_t)b * NN + d) * stride;
    uint2 o;
    o.x = (uint)f2bf(a0) | ((uint)f2bf(a1) << 16);
    o.y = (uint)f2bf(a2) | ((uint)f2bf(a3) << 16);
    *(uint2*)(us + orow + co) = o;
    if (stride == 512) {
        int sy = symm[b * NN + d];
        uint2 v = *(const uint2*)(hb + (size_t)sy * CH + co);
        *(uint2*)(us + orow + 256 + co) = v;
    }
}

// ---------------- MFMA GEMM: C[M][256] = A[M][K] @ Wt^T + bias (relu) (resid) ----------------
// Wt stored as bf16 [256][K] (output-col major). bf16 in, fp32 acc.
// outb (bf16) always written; outf (fp32) optionally; resid: v=(resid+v)*0.5 after relu.

#define BM 128
#define BKT 64
#define LDK 72  // padded row stride (ushorts): only 2-way LDS bank aliasing (free, m136)

__global__ __launch_bounds__(256) void gemm_bf16(const ushort* __restrict__ A,
                                                 const ushort* __restrict__ Wt,
                                                 const float* __restrict__ bias,
                                                 const float* __restrict__ resid,
                                                 ushort* __restrict__ outb,
                                                 float* __restrict__ outf,
                                                 int M, int K, int relu) {
    __shared__ __align__(16) ushort As[BM * LDK];
    __shared__ __align__(16) ushort Bs[BM * LDK];
    int t = threadIdx.x;
    int lane = t & 63, wv = t >> 6;
    int m0 = blockIdx.x * BM;
    int n0 = blockIdx.y * BM;
    int lm = lane & 15, quad = lane >> 4;
    int wm = (wv >> 1) * 64, wn = (wv & 1) * 64;

    f32x4 acc[4][4];
    #pragma unroll
    for (int i = 0; i < 4; i++)
        #pragma unroll
        for (int j = 0; j < 4; j++) acc[i][j] = (f32x4){0.f, 0.f, 0.f, 0.f};

    for (int kt = 0; kt < K; kt += BKT) {
        uint4 av[4], bv[4];
        #pragma unroll
        for (int i = 0; i < 4; i++) {
            int idx = i * 256 + t;
            int row = idx >> 3, ch = idx & 7;
            int ar = m0 + row; if (ar >= M) ar = M - 1;
            av[i] = *(const uint4*)(A + (size_t)ar * K + kt + ch * 8);
            bv[i] = *(const uint4*)(Wt + (size_t)(n0 + row) * K + kt + ch * 8);
        }
        __syncthreads();
        #pragma unroll
        for (int i = 0; i < 4; i++) {
            int idx = i * 256 + t;
            int row = idx >> 3, ch = idx & 7;
            *(uint4*)(&As[row * LDK + ch * 8]) = av[i];
            *(uint4*)(&Bs[row * LDK + ch * 8]) = bv[i];
        }
        __syncthreads();
        #pragma unroll
        for (int ks = 0; ks < 2; ks++) {
            bf16x8_t af[4], bf[4];
            #pragma unroll
            for (int i = 0; i < 4; i++) {
                af[i] = *(const bf16x8_t*)(&As[(wm + i * 16 + lm) * LDK + ks * 32 + quad * 8]);
                bf[i] = *(const bf16x8_t*)(&Bs[(wn + i * 16 + lm) * LDK + ks * 32 + quad * 8]);
            }
            #pragma unroll
            for (int i = 0; i < 4; i++)
                #pragma unroll
                for (int j = 0; j < 4; j++)
                    acc[i][j] = __builtin_amdgcn_mfma_f32_16x16x32_bf16(af[i], bf[j], acc[i][j], 0, 0, 0);
        }
    }

    // epilogue: D layout col=lane&15, row=quad*4+reg
    #pragma unroll
    for (int i = 0; i < 4; i++) {
        #pragma unroll
        for (int r = 0; r < 4; r++) {
            int m = m0 + wm + i * 16 + quad * 4 + r;
            if (m < M) {
                #pragma unroll
                for (int j = 0; j < 4; j++) {
                    int n = n0 + wn + j * 16 + lm;
                    float v = acc[i][j][r] + bias[n];
                    if (relu) v = fmaxf(v, 0.f);
                    if (resid) v = (resid[(size_t)m * CH + n] + v) * 0.5f;
                    outb[(size_t)m * CH + n] = f2bf(v);
                    if (outf) outf[(size_t)m * CH + n] = v;
                }
            }
        }
    }
}

// ---------------- final conv (3 outputs), full fp32 ----------------

__global__ __launch_bounds__(256) void gemm3_kernel(const float* __restrict__ Hf,
                                                    const float* __restrict__ W3,
                                                    float* __restrict__ t3) {
    int wv = threadIdx.x >> 6, lane = threadIdx.x & 63;
    int nd = blockIdx.x * 4 + wv;  // [0, BB*NN)
    float4 hv = *(const float4*)(Hf + (size_t)nd * CH + lane * 4);
    int k0 = lane * 4;
    float s0 = 0.f, s1 = 0.f, s2 = 0.f;
    const float* hp = (const float*)&hv;
    #pragma unroll
    for (int j = 0; j < 4; j++) {
        float h = hp[j];
        s0 += h * W3[(k0 + j) * 3 + 0];
        s1 += h * W3[(k0 + j) * 3 + 1];
        s2 += h * W3[(k0 + j) * 3 + 2];
    }
    #pragma unroll
    for (int off = 32; off; off >>= 1) {
        s0 += __shfl_down(s0, off, 64);
        s1 += __shfl_down(s1, off, 64);
        s2 += __shfl_down(s2, off, 64);
    }
    if (lane == 0) {
        t3[(size_t)nd * 3 + 0] = s0;
        t3[(size_t)nd * 3 + 1] = s1;
        t3[(size_t)nd * 3 + 2] = s2;
    }
}

__global__ __launch_bounds__(256) void agg3_kernel(const float* __restrict__ t3,
                                                   const float* __restrict__ bias,
                                                   const float* __restrict__ dinv,
                                                   const int* __restrict__ rowptr,
                                                   const int* __restrict__ colidx,
                                                   float* __restrict__ out) {
    int i = blockIdx.x * 256 + threadIdx.x;
    if (i >= BB * NN) return;
    int b = i / NN, d = i - b * NN;
    const float* dv = dinv + b * NN;
    const float* t3b = t3 + (size_t)b * NN * 3;
    int r0 = rowptr[(size_t)b * (NN + 1) + d];
    int r1 = rowptr[(size_t)b * (NN + 1) + d + 1];
    float dd = dv[d];
    float a0 = 0.f, a1 = 0.f, a2 = 0.f;
    const int* cb = colidx + (size_t)b * EE;
    for (int j = r0; j < r1; j++) {
        int s = cb[j];
        float w = dv[s] * dd;
        a0 += w * t3b[s * 3 + 0];
        a1 += w * t3b[s * 3 + 1];
        a2 += w * t3b[s * 3 + 2];
    }
    float w = dd * dd;
    a0 += w * t3b[d * 3 + 0] + bias[0];
    a1 += w * t3b[d * 3 + 1] + bias[1];
    a2 += w * t3b[d * 3 + 2] + bias[2];
    size_t o = (size_t)i * 3;
    out[o + 0] = a0;
    out[o + 1] = a1;
    out[o + 2] = a2;
}

// ---------------- host ----------------

extern "C" void kernel_launch(void* const* d_in, const int* in_sizes, int n_in,
                              void* d_out, int out_size, void* d_ws, size_t ws_size,
                              hipStream_t stream) {
    const float* x     = (const float*)d_in[0];
    const int*   edge  = (const int*)d_in[1];
    const int*   symm  = (const int*)d_in[2];
    const float* linW  = (const float*)d_in[3];
    const float* linb  = (const float*)d_in[4];
    const float* c1W   = (const float*)d_in[5];
    const float* c1b   = (const float*)d_in[6];
    const float* blkW  = (const float*)d_in[7];
    const float* blkWs = (const float*)d_in[8];
    const float* blkb  = (const float*)d_in[9];
    const float* c3W   = (const float*)d_in[10];
    const float* c3b   = (const float*)d_in[11];

    char* ws = (char*)d_ws;
    size_t off = 0;
    auto alloc = [&](size_t bytes) -> void* {
        void* p = ws + off;
        off += (bytes + 255) & ~(size_t)255;
        return p;
    };
    ushort* xp     = (ushort*)alloc((size_t)BB * NN * 1024 * 2);  // 164 MB; us aliases (dead after lin)
    ushort* us     = xp;                                          // [B*N][512] bf16 (82 MB)
    ushort* Hb     = (ushort*)alloc((size_t)BB * NN * CH * 2);
    ushort* y      = (ushort*)alloc((size_t)BB * NN * CH * 2);
    float*  t3     = (float*) alloc((size_t)BB * NN * 3 * 4);
    ushort* linWt  = (ushort*)alloc((size_t)256 * 1024 * 2);
    ushort* c1Wt   = (ushort*)alloc((size_t)256 * 256 * 2);
    ushort* blkWc  = (ushort*)alloc((size_t)12 * 256 * 512 * 2);
    int*    cnt    = (int*)  alloc((size_t)BB * NN * 4);
    int*    fill   = (int*)  alloc((size_t)BB * NN * 4);
    float*  dinv   = (float*)alloc((size_t)BB * NN * 4);
    int*    rowptr = (int*)  alloc((size_t)BB * (NN + 1) * 4);
    int*    colidx = (int*)  alloc((size_t)BB * EE * 4);

    float* Hf   = (float*)d_out;                  // [B,N,256] float (output 0 = final h)
    float* out2 = Hf + (size_t)BB * NN * CH;      // [B,N,3] float (output 1)

    // CSR + norm
    init_zero_kernel<<<(BB * NN + 255) / 256, 256, 0, stream>>>(cnt, fill);
    count_kernel<<<(BB * EE + 255) / 256, 256, 0, stream>>>(edge, cnt);
    dinv_kernel<<<(BB * NN + 255) / 256, 256, 0, stream>>>(cnt, dinv);
    scan_kernel<<<BB, 256, 0, stream>>>(cnt, rowptr);
    fill_kernel<<<(BB * EE + 255) / 256, 256, 0, stream>>>(edge, rowptr, fill, colidx);

    // weight conversion/transpose (float -> bf16)
    wt_lin_kernel<<<(256 * 1024 + 255) / 256, 256, 0, stream>>>(linW, linWt);
    wt_sq_kernel<<<(65536 + 255) / 256, 256, 0, stream>>>(c1W, c1Wt);
    wt_cat_kernel<<<(12 * 256 * 512 + 255) / 256, 256, 0, stream>>>(blkW, blkWs, blkWc);

    dim3 ggrid((BB * NN) / BM, 2);  // 625 x 2
    dim3 agrid(NN / 4, BB);         // 5000 x 4

    // lin: pad+convert all batches, one GEMM (K=1024) -> Hb (bf16)
    pad_x_kernel<<<(int)(((size_t)BB * NN * 1024 + 255) / 256), 256, 0, stream>>>(x, xp);
    gemm_bf16<<<ggrid, 256, 0, stream>>>(xp, linWt, linb, nullptr, Hb, nullptr,
                                         BB * NN, 1024, 0);

    // conv1: u = P@x_lin; h = relu(u@c1W + c1b) -> Hb + Hf
    gather_kernel<<<agrid, 256, 0, stream>>>(Hb, nullptr, dinv, rowptr, colidx, us, 256);
    gemm_bf16<<<ggrid, 256, 0, stream>>>(us, c1Wt, c1b, nullptr, Hb, Hf,
                                         BB * NN, 256, 1);

    // 6 GBottleneck blocks: y = relu([P@h|h[symm]]@Wc0 + b0);
    //                       h = (h + relu([P@y|y[symm]]@Wc1 + b1)) * 0.5
    for (int i = 0; i < 6; i++) {
        const ushort* Wc0 = blkWc + (size_t)(2 * i) * 131072;
        const float*  b0  = blkb  + (size_t)(2 * i) * 256;
        const ushort* Wc1 = blkWc + (size_t)(2 * i + 1) * 131072;
        const float*  b1  = blkb  + (size_t)(2 * i + 1) * 256;

        gather_kernel<<<agrid, 256, 0, stream>>>(Hb, symm, dinv, rowptr, colidx, us, 512);
        gemm_bf16<<<ggrid, 256, 0, stream>>>(us, Wc0, b0, nullptr, y, nullptr,
                                             BB * NN, 512, 1);

        gather_kernel<<<agrid, 256, 0, stream>>>(y, symm, dinv, rowptr, colidx, us, 512);
        gemm_bf16<<<ggrid, 256, 0, stream>>>(us, Wc1, b1, Hf, Hb, Hf,
                                             BB * NN, 512, 1);
    }

    // conv3 in fp32 -> out2
    gemm3_kernel<<<(BB * NN) / 4, 256, 0, stream>>>(Hf, c3W, t3);
    agg3_kernel<<<(BB * NN + 255) / 256, 256, 0, stream>>>(t3, c3b, dinv,
                                                           rowptr, colidx, out2);

    (void)in_sizes; (void)n_in; (void)out_size; (void)ws_size;
}

// Round 4
// 3182.727 us; speedup vs baseline: 1.3800x; 1.3800x over previous
//
#include <hip/hip_runtime.h>

#define NN 20000
#define EE 120000
#define BB 4
#define CH 256

typedef unsigned int uint;
typedef unsigned short ushort;

typedef __attribute__((ext_vector_type(8))) short bf16x8_t;
typedef __attribute__((ext_vector_type(4))) float f32x4;

__device__ __forceinline__ float bf2f(ushort h) {
    union { uint u; float f; } v; v.u = ((uint)h) << 16; return v.f;
}
__device__ __forceinline__ ushort f2bf(float f) {
    union { float f; uint u; } v; v.f = f;
    uint u = v.u;
    uint r = (u + 0x7fffu + ((u >> 16) & 1u)) >> 16;
    return (ushort)r;
}

// ---------------- CSR build ----------------

__global__ __launch_bounds__(256) void init_zero_kernel(int* cnt, int* fill) {
    int i = blockIdx.x * 256 + threadIdx.x;
    if (i < BB * NN) { cnt[i] = 0; fill[i] = 0; }
}

__global__ __launch_bounds__(256) void count_kernel(const int* __restrict__ edge, int* cnt) {
    int i = blockIdx.x * 256 + threadIdx.x;
    if (i >= BB * EE) return;
    int b = i / EE, e = i - b * EE;
    int dst = edge[(size_t)b * 2 * EE + EE + e];
    atomicAdd(&cnt[b * NN + dst], 1);
}

__global__ __launch_bounds__(256) void dinv_kernel(const int* __restrict__ cnt, float* dinv) {
    int i = blockIdx.x * 256 + threadIdx.x;
    if (i < BB * NN) dinv[i] = rsqrtf((float)(cnt[i] + 1));
}

__global__ __launch_bounds__(256) void scan_kernel(const int* __restrict__ cnt, int* rowptr) {
    int b = blockIdx.x;
    int t = threadIdx.x;
    int lane = t & 63, wv = t >> 6;
    __shared__ int wsum[4];
    int carry = 0;
    for (int base = 0; base < NN; base += 256) {
        int v = (base + t < NN) ? cnt[b * NN + base + t] : 0;
        int incl = v;
        #pragma unroll
        for (int off = 1; off < 64; off <<= 1) {
            int u = __shfl_up(incl, off, 64);
            if (lane >= off) incl += u;
        }
        if (lane == 63) wsum[wv] = incl;
        __syncthreads();
        int wadd = 0;
        for (int w2 = 0; w2 < wv; w2++) wadd += wsum[w2];
        int tot = wsum[0] + wsum[1] + wsum[2] + wsum[3];
        if (base + t < NN) rowptr[(size_t)b * (NN + 1) + base + t] = carry + wadd + incl - v;
        carry += tot;
        __syncthreads();
    }
    if (t == 0) rowptr[(size_t)b * (NN + 1) + NN] = carry;
}

__global__ __launch_bounds__(256) void fill_kernel(const int* __restrict__ edge,
                                                   const int* __restrict__ rowptr,
                                                   int* fill, int* colidx) {
    int i = blockIdx.x * 256 + threadIdx.x;
    if (i >= BB * EE) return;
    int b = i / EE, e = i - b * EE;
    int src = edge[(size_t)b * 2 * EE + e];
    int dst = edge[(size_t)b * 2 * EE + EE + e];
    int pos = rowptr[(size_t)b * (NN + 1) + dst] + atomicAdd(&fill[b * NN + dst], 1);
    colidx[(size_t)b * EE + pos] = src;
}

// ---------------- weight prep (float32 -> bf16) ----------------

__global__ __launch_bounds__(256) void wt_sq_kernel(const float* __restrict__ src,
                                                    ushort* __restrict__ dst) {
    int i = blockIdx.x * 256 + threadIdx.x;
    if (i >= 65536) return;
    int n = i >> 8, k = i & 255;
    dst[i] = f2bf(src[(k << 8) + n]);
}

// concat [W;Ws] per layer: dst bf16 [12][256 n][512 k]
__global__ __launch_bounds__(256) void wt_cat_kernel(const float* __restrict__ W,
                                                     const float* __restrict__ Ws,
                                                     ushort* __restrict__ dst) {
    int i = blockIdx.x * 256 + threadIdx.x;
    if (i >= 12 * 256 * 512) return;
    int mat = i >> 17;
    int rem = i & 131071;
    int n = rem >> 9, k = rem & 511;
    float v = (k < 256) ? W[(mat << 16) + (k << 8) + n]
                        : Ws[(mat << 16) + ((k - 256) << 8) + n];
    dst[i] = f2bf(v);
}

// src float [963][256] -> dst bf16 [256][1024] (zero-padded K)
__global__ __launch_bounds__(256) void wt_lin_kernel(const float* __restrict__ src,
                                                     ushort* __restrict__ dst) {
    int i = blockIdx.x * 256 + threadIdx.x;
    if (i >= 256 * 1024) return;
    int n = i >> 10, k = i & 1023;
    dst[i] = (k < 963) ? f2bf(src[k * 256 + n]) : (ushort)0;
}

// x float [80000][963] -> xp bf16 [80000][1024] zero-padded
__global__ __launch_bounds__(256) void pad_x_kernel(const float* __restrict__ x,
                                                    ushort* __restrict__ xp) {
    size_t i = (size_t)blockIdx.x * 256 + threadIdx.x;
    if (i >= (size_t)BB * NN * 1024) return;
    size_t row = i >> 10;
    int k = (int)(i & 1023);
    xp[i] = (k < 963) ? f2bf(x[row * 963 + k]) : (ushort)0;
}

// ---------------- gather: us[d] = [ P@h (256ch) | h[symm] (256ch, optional) ] ----------------

__global__ __launch_bounds__(256) void gather_kernel(const ushort* __restrict__ h,
                                                     const int* __restrict__ symm,
                                                     const float* __restrict__ dinv,
                                                     const int* __restrict__ rowptr,
                                                     const int* __restrict__ colidx,
                                                     ushort* __restrict__ us,
                                                     int stride) {  // 256 or 512
    int wv = threadIdx.x >> 6, lane = threadIdx.x & 63;
    int d = blockIdx.x * 4 + wv;
    int b = blockIdx.y;
    const ushort* hb = h + (size_t)b * NN * CH;
    const float* dv = dinv + b * NN;
    int co = lane * 4;
    int r0 = rowptr[(size_t)b * (NN + 1) + d];
    int r1 = rowptr[(size_t)b * (NN + 1) + d + 1];
    float dd = dv[d];
    const int* cb = colidx + (size_t)b * EE;
    float a0, a1, a2, a3;
    {   // self loop
        float w = dd * dd;
        uint2 v = *(const uint2*)(hb + (size_t)d * CH + co);
        a0 = w * bf2f((ushort)(v.x & 0xffff));
        a1 = w * bf2f((ushort)(v.x >> 16));
        a2 = w * bf2f((ushort)(v.y & 0xffff));
        a3 = w * bf2f((ushort)(v.y >> 16));
    }
    for (int j = r0; j < r1; j++) {
        int s = cb[j];
        float w = dv[s] * dd;
        uint2 v = *(const uint2*)(hb + (size_t)s * CH + co);
        a0 += w * bf2f((ushort)(v.x & 0xffff));
        a1 += w * bf2f((ushort)(v.x >> 16));
        a2 += w * bf2f((ushort)(v.y & 0xffff));
        a3 += w * bf2f((ushort)(v.y >> 16));
    }
    size_t orow = ((size_t)b * NN + d) * stride;
    uint2 o;
    o.x = (uint)f2bf(a0) | ((uint)f2bf(a1) << 16);
    o.y = (uint)f2bf(a2) | ((uint)f2bf(a3) << 16);
    *(uint2*)(us + orow + co) = o;
    if (stride == 512) {
        int sy = symm[b * NN + d];
        uint2 v = *(const uint2*)(hb + (size_t)sy * CH + co);
        *(uint2*)(us + orow + 256 + co) = v;
    }
}

// ---------------- MFMA GEMM: C[M][256] = A[M][K] @ Wt^T + bias (relu) (resid avg) ----------
// 512 threads, BM=128, BN=256 (full width), BK=64. XOR-swizzled LDS (LDK=64, no pad).
// Epilogue: per-wave LDS repack -> coalesced uint4 stores. resid (bf16): v=(resid+v)*0.5.

#define BM 128

__global__ __launch_bounds__(512, 4) void gemm_bf16(const ushort* __restrict__ A,
                                                    const ushort* __restrict__ Wt,
                                                    const float* __restrict__ bias,
                                                    const ushort* __restrict__ resid,
                                                    ushort* __restrict__ outb,
                                                    int M, int K, int relu) {
    __shared__ __align__(16) ushort smem[32768];  // 64 KB: staging 48 KB; epilogue 8 KB/wave
    ushort* As = smem;            // [128][64] swizzled
    ushort* Bs = smem + 128 * 64; // [256][64] swizzled
    int t = threadIdx.x;
    int lane = t & 63, wv = t >> 6;
    int m0 = blockIdx.x * BM;
    int lm = lane & 15, quad = lane >> 4;
    int wm = (wv >> 2) * 64;   // 2 m-halves
    int wn = (wv & 3) * 64;    // 4 n-quarters

    f32x4 acc[4][4];
    #pragma unroll
    for (int i = 0; i < 4; i++)
        #pragma unroll
        for (int j = 0; j < 4; j++) acc[i][j] = (f32x4){0.f, 0.f, 0.f, 0.f};

    for (int kt = 0; kt < K; kt += 64) {
        uint4 av[2], bv[4];
        #pragma unroll
        for (int p = 0; p < 2; p++) {
            int idx = p * 512 + t;
            int row = idx >> 3, ch = idx & 7;
            av[p] = *(const uint4*)(A + (size_t)(m0 + row) * K + kt + ch * 8);
        }
        #pragma unroll
        for (int p = 0; p < 4; p++) {
            int idx = p * 512 + t;
            int row = idx >> 3, ch = idx & 7;
            bv[p] = *(const uint4*)(Wt + (size_t)row * K + kt + ch * 8);
        }
        __syncthreads();
        #pragma unroll
        for (int p = 0; p < 2; p++) {
            int idx = p * 512 + t;
            int row = idx >> 3, ch = idx & 7;
            *(uint4*)(As + row * 64 + ((ch ^ (row & 7)) << 3)) = av[p];
        }
        #pragma unroll
        for (int p = 0; p < 4; p++) {
            int idx = p * 512 + t;
            int row = idx >> 3, ch = idx & 7;
            *(uint4*)(Bs + row * 64 + ((ch ^ (row & 7)) << 3)) = bv[p];
        }
        __syncthreads();
        #pragma unroll
        for (int ks = 0; ks < 2; ks++) {
            bf16x8_t af[4];
            #pragma unroll
            for (int i = 0; i < 4; i++) {
                int row = wm + i * 16 + lm;
                int chunk = (ks * 4 + quad) ^ (row & 7);
                af[i] = *(const bf16x8_t*)(As + row * 64 + chunk * 8);
            }
            #pragma unroll
            for (int j = 0; j < 4; j++) {
                int row = wn + j * 16 + lm;
                int chunk = (ks * 4 + quad) ^ (row & 7);
                bf16x8_t bfr = *(const bf16x8_t*)(Bs + row * 64 + chunk * 8);
                #pragma unroll
                for (int i = 0; i < 4; i++)
                    acc[i][j] = __builtin_amdgcn_mfma_f32_16x16x32_bf16(af[i], bfr, acc[i][j], 0, 0, 0);
            }
        }
    }

    // ---- epilogue ----
    float bj[4];
    #pragma unroll
    for (int j = 0; j < 4; j++) bj[j] = bias[wn + j * 16 + lm];
    __syncthreads();  // all waves done reading As/Bs before eb overwrite
    ushort* eb = smem + wv * 4096;  // 64 rows x 64 cols, chunk-swizzled by row&7
    #pragma unroll
    for (int i = 0; i < 4; i++) {
        #pragma unroll
        for (int r = 0; r < 4; r++) {
            int row = i * 16 + quad * 4 + r;  // 0..63
            int sw = row & 7;
            #pragma unroll
            for (int j = 0; j < 4; j++) {
                int col = j * 16 + lm;
                int scol = ((((col >> 3) ^ sw)) << 3) | (col & 7);
                float v = acc[i][j][r] + bj[j];
                if (relu) v = fmaxf(v, 0.f);
                eb[row * 64 + scol] = f2bf(v);
            }
        }
    }
    // wave-local readback + coalesced store (8 rows x 128B full lines per instr)
    int rl = lane >> 3, c8 = lane & 7;
    #pragma unroll
    for (int s = 0; s < 8; s++) {
        int row = s * 8 + rl;  // 0..63
        int chunk = c8 ^ (row & 7);
        uint4 v = *(const uint4*)(eb + row * 64 + chunk * 8);
        size_t ga = (size_t)(m0 + wm + row) * CH + wn + c8 * 8;
        if (resid) {
            uint4 h = *(const uint4*)(resid + ga);
            uint res[4];
            const uint* vp = (const uint*)&v;
            const uint* hp = (const uint*)&h;
            #pragma unroll
            for (int w = 0; w < 4; w++) {
                float y0 = bf2f((ushort)(vp[w] & 0xffff));
                float y1 = bf2f((ushort)(vp[w] >> 16));
                float h0 = bf2f((ushort)(hp[w] & 0xffff));
                float h1 = bf2f((ushort)(hp[w] >> 16));
                res[w] = (uint)f2bf((h0 + y0) * 0.5f) | ((uint)f2bf((h1 + y1) * 0.5f) << 16);
            }
            v = *(uint4*)res;
        }
        *(uint4*)(outb + ga) = v;
    }
}

// ---------------- h (bf16) -> output 0 (fp32) ----------------

__global__ __launch_bounds__(256) void cvt_kernel(const ushort* __restrict__ Hb,
                                                  float* __restrict__ Hf) {
    size_t i = ((size_t)blockIdx.x * 256 + threadIdx.x) * 4;
    if (i >= (size_t)BB * NN * CH) return;
    uint2 v = *(const uint2*)(Hb + i);
    float4 o;
    o.x = bf2f((ushort)(v.x & 0xffff));
    o.y = bf2f((ushort)(v.x >> 16));
    o.z = bf2f((ushort)(v.y & 0xffff));
    o.w = bf2f((ushort)(v.y >> 16));
    *(float4*)(Hf + i) = o;
}

// ---------------- final conv (3 outputs), fp32 math from bf16 h ----------------

__global__ __launch_bounds__(256) void gemm3_kernel(const ushort* __restrict__ Hb,
                                                    const float* __restrict__ W3,
                                                    float* __restrict__ t3) {
    int wv = threadIdx.x >> 6, lane = threadIdx.x & 63;
    int nd = blockIdx.x * 4 + wv;  // [0, BB*NN)
    uint2 hv = *(const uint2*)(Hb + (size_t)nd * CH + lane * 4);
    float hp[4];
    hp[0] = bf2f((ushort)(hv.x & 0xffff));
    hp[1] = bf2f((ushort)(hv.x >> 16));
    hp[2] = bf2f((ushort)(hv.y & 0xffff));
    hp[3] = bf2f((ushort)(hv.y >> 16));
    int k0 = lane * 4;
    float s0 = 0.f, s1 = 0.f, s2 = 0.f;
    #pragma unroll
    for (int j = 0; j < 4; j++) {
        float h = hp[j];
        s0 += h * W3[(k0 + j) * 3 + 0];
        s1 += h * W3[(k0 + j) * 3 + 1];
        s2 += h * W3[(k0 + j) * 3 + 2];
    }
    #pragma unroll
    for (int off = 32; off; off >>= 1) {
        s0 += __shfl_down(s0, off, 64);
        s1 += __shfl_down(s1, off, 64);
        s2 += __shfl_down(s2, off, 64);
    }
    if (lane == 0) {
        t3[(size_t)nd * 3 + 0] = s0;
        t3[(size_t)nd * 3 + 1] = s1;
        t3[(size_t)nd * 3 + 2] = s2;
    }
}

__global__ __launch_bounds__(256) void agg3_kernel(const float* __restrict__ t3,
                                                   const float* __restrict__ bias,
                                                   const float* __restrict__ dinv,
                                                   const int* __restrict__ rowptr,
                                                   const int* __restrict__ colidx,
                                                   float* __restrict__ out) {
    int i = blockIdx.x * 256 + threadIdx.x;
    if (i >= BB * NN) return;
    int b = i / NN, d = i - b * NN;
    const float* dv = dinv + b * NN;
    const float* t3b = t3 + (size_t)b * NN * 3;
    int r0 = rowptr[(size_t)b * (NN + 1) + d];
    int r1 = rowptr[(size_t)b * (NN + 1) + d + 1];
    float dd = dv[d];
    float a0 = 0.f, a1 = 0.f, a2 = 0.f;
    const int* cb = colidx + (size_t)b * EE;
    for (int j = r0; j < r1; j++) {
        int s = cb[j];
        float w = dv[s] * dd;
        a0 += w * t3b[s * 3 + 0];
        a1 += w * t3b[s * 3 + 1];
        a2 += w * t3b[s * 3 + 2];
    }
    float w = dd * dd;
    a0 += w * t3b[d * 3 + 0] + bias[0];
    a1 += w * t3b[d * 3 + 1] + bias[1];
    a2 += w * t3b[d * 3 + 2] + bias[2];
    size_t o = (size_t)i * 3;
    out[o + 0] = a0;
    out[o + 1] = a1;
    out[o + 2] = a2;
}

// ---------------- host ----------------

extern "C" void kernel_launch(void* const* d_in, const int* in_sizes, int n_in,
                              void* d_out, int out_size, void* d_ws, size_t ws_size,
                              hipStream_t stream) {
    const float* x     = (const float*)d_in[0];
    const int*   edge  = (const int*)d_in[1];
    const int*   symm  = (const int*)d_in[2];
    const float* linW  = (const float*)d_in[3];
    const float* linb  = (const float*)d_in[4];
    const float* c1W   = (const float*)d_in[5];
    const float* c1b   = (const float*)d_in[6];
    const float* blkW  = (const float*)d_in[7];
    const float* blkWs = (const float*)d_in[8];
    const float* blkb  = (const float*)d_in[9];
    const float* c3W   = (const float*)d_in[10];
    const float* c3b   = (const float*)d_in[11];

    char* ws = (char*)d_ws;
    size_t off = 0;
    auto alloc = [&](size_t bytes) -> void* {
        void* p = ws + off;
        off += (bytes + 255) & ~(size_t)255;
        return p;
    };
    ushort* xp     = (ushort*)alloc((size_t)BB * NN * 1024 * 2);  // 164 MB; us aliases after lin
    ushort* us     = xp;                                          // [B*N][512] bf16 (82 MB)
    ushort* Hb     = (ushort*)alloc((size_t)BB * NN * CH * 2);
    ushort* y      = (ushort*)alloc((size_t)BB * NN * CH * 2);
    float*  t3     = (float*) alloc((size_t)BB * NN * 3 * 4);
    ushort* linWt  = (ushort*)alloc((size_t)256 * 1024 * 2);
    ushort* c1Wt   = (ushort*)alloc((size_t)256 * 256 * 2);
    ushort* blkWc  = (ushort*)alloc((size_t)12 * 256 * 512 * 2);
    int*    cnt    = (int*)  alloc((size_t)BB * NN * 4);
    int*    fill   = (int*)  alloc((size_t)BB * NN * 4);
    float*  dinv   = (float*)alloc((size_t)BB * NN * 4);
    int*    rowptr = (int*)  alloc((size_t)BB * (NN + 1) * 4);
    int*    colidx = (int*)  alloc((size_t)BB * EE * 4);

    float* Hf   = (float*)d_out;                  // [B,N,256] float (output 0 = final h)
    float* out2 = Hf + (size_t)BB * NN * CH;      // [B,N,3] float (output 1)

    // CSR + norm
    init_zero_kernel<<<(BB * NN + 255) / 256, 256, 0, stream>>>(cnt, fill);
    count_kernel<<<(BB * EE + 255) / 256, 256, 0, stream>>>(edge, cnt);
    dinv_kernel<<<(BB * NN + 255) / 256, 256, 0, stream>>>(cnt, dinv);
    scan_kernel<<<BB, 256, 0, stream>>>(cnt, rowptr);
    fill_kernel<<<(BB * EE + 255) / 256, 256, 0, stream>>>(edge, rowptr, fill, colidx);

    // weight conversion/transpose (float -> bf16)
    wt_lin_kernel<<<(256 * 1024 + 255) / 256, 256, 0, stream>>>(linW, linWt);
    wt_sq_kernel<<<(65536 + 255) / 256, 256, 0, stream>>>(c1W, c1Wt);
    wt_cat_kernel<<<(12 * 256 * 512 + 255) / 256, 256, 0, stream>>>(blkW, blkWs, blkWc);

    int ggrid = (BB * NN) / BM;     // 625 blocks, full N=256 per block
    dim3 agrid(NN / 4, BB);         // 5000 x 4

    // lin: pad+convert all batches, one GEMM (K=1024) -> Hb (bf16)
    pad_x_kernel<<<(int)(((size_t)BB * NN * 1024 + 255) / 256), 256, 0, stream>>>(x, xp);
    gemm_bf16<<<ggrid, 512, 0, stream>>>(xp, linWt, linb, nullptr, Hb, BB * NN, 1024, 0);

    // conv1: u = P@x_lin; h = relu(u@c1W + c1b) -> Hb
    gather_kernel<<<agrid, 256, 0, stream>>>(Hb, nullptr, dinv, rowptr, colidx, us, 256);
    gemm_bf16<<<ggrid, 512, 0, stream>>>(us, c1Wt, c1b, nullptr, Hb, BB * NN, 256, 1);

    // 6 GBottleneck blocks: y = relu([P@h|h[symm]]@Wc0 + b0);
    //                       h = (h + relu([P@y|y[symm]]@Wc1 + b1)) * 0.5
    for (int i = 0; i < 6; i++) {
        const ushort* Wc0 = blkWc + (size_t)(2 * i) * 131072;
        const float*  b0  = blkb  + (size_t)(2 * i) * 256;
        const ushort* Wc1 = blkWc + (size_t)(2 * i + 1) * 131072;
        const float*  b1  = blkb  + (size_t)(2 * i + 1) * 256;

        gather_kernel<<<agrid, 256, 0, stream>>>(Hb, symm, dinv, rowptr, colidx, us, 512);
        gemm_bf16<<<ggrid, 512, 0, stream>>>(us, Wc0, b0, nullptr, y, BB * NN, 512, 1);

        gather_kernel<<<agrid, 256, 0, stream>>>(y, symm, dinv, rowptr, colidx, us, 512);
        gemm_bf16<<<ggrid, 512, 0, stream>>>(us, Wc1, b1, Hb, Hb, BB * NN, 512, 1);
    }

    // output 0: h fp32
    cvt_kernel<<<(int)(((size_t)BB * NN * CH / 4 + 255) / 256), 256, 0, stream>>>(Hb, Hf);

    // conv3 -> out2 (fp32)
    gemm3_kernel<<<(BB * NN) / 4, 256, 0, stream>>>(Hb, c3W, t3);
    agg3_kernel<<<(BB * NN + 255) / 256, 256, 0, stream>>>(t3, c3b, dinv,
                                                           rowptr, colidx, out2);

    (void)in_sizes; (void)n_in; (void)out_size; (void)ws_size;
}